// Round 1
// baseline (1050.505 us; speedup 1.0000x reference)
//
#include <hip/hip_runtime.h>

typedef __bf16 bf16x8 __attribute__((ext_vector_type(8)));
typedef short short8_t __attribute__((ext_vector_type(8)));
typedef float f32x4 __attribute__((ext_vector_type(4)));
typedef float f32x4_t __attribute__((ext_vector_type(4)));
typedef unsigned short us4_t __attribute__((ext_vector_type(4)));

#define SCALE 0.08838834764831845f  // 1/sqrt(128)

__device__ __forceinline__ float b2f(unsigned short u) {
  union { unsigned int i; float f; } v; v.i = ((unsigned int)u) << 16; return v.f;
}
__device__ __forceinline__ unsigned short f2b(float f) {
  union { float f; unsigned int i; } v; v.f = f;
  unsigned int r = v.i + 0x7fffu + ((v.i >> 16) & 1u);
  return (unsigned short)(r >> 16);
}

__device__ __forceinline__ f32x4 mfma16(short8_t a, short8_t b, f32x4 c) {
  return __builtin_amdgcn_mfma_f32_16x16x32_bf16(
      __builtin_bit_cast(bf16x8, a), __builtin_bit_cast(bf16x8, b), c, 0, 0, 0);
}

typedef __attribute__((address_space(1))) const void gas_t;
typedef __attribute__((address_space(3))) void las_t;
__device__ __forceinline__ void gload16(const unsigned short* g, unsigned short* l) {
  __builtin_amdgcn_global_load_lds((gas_t*)g, (las_t*)l, 16, 0, 0);
}

// ---------------- fp32 -> bf16 convert ----------------
__global__ void cvt_kernel(const float* __restrict__ src, unsigned short* __restrict__ dst, int n4) {
  for (int i = blockIdx.x * blockDim.x + threadIdx.x; i < n4; i += gridDim.x * blockDim.x) {
    f32x4_t v = *(const f32x4_t*)(src + (size_t)i * 4);
    us4_t o;
    o[0] = f2b(v[0]); o[1] = f2b(v[1]); o[2] = f2b(v[2]); o[3] = f2b(v[3]);
    *(us4_t*)(dst + (size_t)i * 4) = o;
  }
}

// ---------------- 128x128 bf16 GEMM core (C = A * Bt^T) ----------------
// A: MxK bf16 row-major.  Bt: NxK bf16 row-major.  K % 32 == 0.
template <bool BF16OUT>
__device__ __forceinline__ void gemm128(const unsigned short* __restrict__ A,
                                        const unsigned short* __restrict__ Bt,
                                        void* __restrict__ Cout,
                                        int m0, int n0, int K, int ldc) {
  __shared__ __align__(16) unsigned short As[128 * 32];
  __shared__ __align__(16) unsigned short Bs[128 * 32];
  const int tid = threadIdx.x;
  const int wave = tid >> 6, lane = tid & 63;
  const int ln = lane & 15, g = lane >> 4;
  const int wm = (wave >> 1) * 64, wn = (wave & 1) * 64;

  // staging: rounds i=0,1; wave w covers LDS bytes [(i*4+w)*1024, +1024)
  const int rA0 = wave * 16 + (lane >> 2);
  const int rA1 = 64 + wave * 16 + (lane >> 2);
  const int colx = (lane & 3) * 8;
  const unsigned short* gA0 = A + (size_t)(m0 + rA0) * K + colx;
  const unsigned short* gA1 = A + (size_t)(m0 + rA1) * K + colx;
  const unsigned short* gB0 = Bt + (size_t)(n0 + rA0) * K + colx;
  const unsigned short* gB1 = Bt + (size_t)(n0 + rA1) * K + colx;
  unsigned short* lA0 = As + wave * 512;
  unsigned short* lA1 = As + 2048 + wave * 512;
  unsigned short* lB0 = Bs + wave * 512;
  unsigned short* lB1 = Bs + 2048 + wave * 512;

  f32x4 acc[4][4] = {};

  for (int k0 = 0; k0 < K; k0 += 32) {
    gload16(gA0 + k0, lA0);
    gload16(gA1 + k0, lA1);
    gload16(gB0 + k0, lB0);
    gload16(gB1 + k0, lB1);
    __syncthreads();
    short8_t a[4], b[4];
#pragma unroll
    for (int i = 0; i < 4; ++i)
      a[i] = *(const short8_t*)(As + (wm + i * 16 + ln) * 32 + g * 8);
#pragma unroll
    for (int j = 0; j < 4; ++j)
      b[j] = *(const short8_t*)(Bs + (wn + j * 16 + ln) * 32 + g * 8);
#pragma unroll
    for (int i = 0; i < 4; ++i)
#pragma unroll
      for (int j = 0; j < 4; ++j)
        acc[i][j] = mfma16(a[i], b[j], acc[i][j]);
    __syncthreads();
  }

#pragma unroll
  for (int i = 0; i < 4; ++i) {
#pragma unroll
    for (int j = 0; j < 4; ++j) {
#pragma unroll
      for (int r = 0; r < 4; ++r) {
        int row = m0 + wm + i * 16 + g * 4 + r;
        int col = n0 + wn + j * 16 + ln;
        if (BF16OUT)
          ((unsigned short*)Cout)[(size_t)row * ldc + col] = f2b(acc[i][j][r]);
        else
          ((float*)Cout)[(size_t)row * ldc + col] = acc[i][j][r];
      }
    }
  }
}

// QKV combined: grid (48, 32). bx<32 -> Q, 32..39 -> K, 40..47 -> V.
__global__ __launch_bounds__(256) void gemm_qkv_kernel(
    const unsigned short* __restrict__ xb, const unsigned short* __restrict__ wqb,
    const unsigned short* __restrict__ wkb, const unsigned short* __restrict__ wvb,
    unsigned short* __restrict__ xq, unsigned short* __restrict__ xk,
    unsigned short* __restrict__ xv) {
  int bx = blockIdx.x, by = blockIdx.y;
  const unsigned short* Bt; unsigned short* C; int ldc, n0;
  if (bx < 32)      { Bt = wqb; C = xq; ldc = 4096; n0 = bx * 128; }
  else if (bx < 40) { Bt = wkb; C = xk; ldc = 1024; n0 = (bx - 32) * 128; }
  else              { Bt = wvb; C = xv; ldc = 1024; n0 = (bx - 40) * 128; }
  gemm128<true>(xb, Bt, C, by * 128, n0, 4096, ldc);
}

__global__ __launch_bounds__(256) void gemm_o_kernel(
    const unsigned short* __restrict__ ao, const unsigned short* __restrict__ wob,
    float* __restrict__ out) {
  gemm128<false>(ao, wob, out, blockIdx.y * 128, blockIdx.x * 128, 4096, 4096);
}

// ---------------- RoPE (in-place on bf16, recomputed every call) ----------------
template <int NH>
__global__ void rope_kernel(unsigned short* __restrict__ p, const float* __restrict__ fr,
                            int nchunks) {
  for (int c = blockIdx.x * blockDim.x + threadIdx.x; c < nchunks;
       c += gridDim.x * blockDim.x) {
    size_t e = (size_t)c * 8;
    int f0 = (c & 15) * 4;            // pair index base within head
    int rest = (int)(e >> 7);         // (b*2048+s)*NH + h
    int s = (rest / NH) & 2047;
    unsigned short* ptr = p + e;
    short8_t v = *(short8_t*)ptr;
    const float* cosp = fr + (size_t)s * 64 + f0;
    const float* sinp = cosp + 131072;
#pragma unroll
    for (int j = 0; j < 4; ++j) {
      float re = b2f((unsigned short)v[2 * j]);
      float im = b2f((unsigned short)v[2 * j + 1]);
      float cc = cosp[j], ss = sinp[j];
      v[2 * j]     = (short)f2b(re * cc - im * ss);
      v[2 * j + 1] = (short)f2b(re * ss + im * cc);
    }
    *(short8_t*)ptr = v;
  }
}

// ---------------- flash attention ----------------
// grid (32 qtiles, 32 heads, 2 batch), 256 threads (4 waves x 16 q-rows)
__global__ __launch_bounds__(256) void attn_kernel(
    const unsigned short* __restrict__ xq, const unsigned short* __restrict__ xk,
    const unsigned short* __restrict__ xv, unsigned short* __restrict__ ao) {
  __shared__ __align__(16) unsigned short Klds[64 * 136];  // padded stride 136
  __shared__ __align__(16) unsigned short VT[128 * 72];    // V^T, padded stride 72
  __shared__ __align__(16) unsigned short Plds[4 * 16 * 72];

  const int tid = threadIdx.x;
  const int wave = tid >> 6, lane = tid & 63;
  const int ln = lane & 15, g = lane >> 4;
  const int bx = blockIdx.x, h = blockIdx.y, b = blockIdx.z;
  const int hkv = h >> 2;
  const int q0 = bx * 64;

  // Q fragments in registers: rows q0 + wave*16 + ln, k-slices per hd-step
  const unsigned short* qb = xq + ((size_t)(b * 2048 + q0 + wave * 16 + ln) * 32 + h) * 128;
  short8_t qf[4];
#pragma unroll
  for (int s = 0; s < 4; ++s) qf[s] = *(const short8_t*)(qb + s * 32 + g * 8);

  f32x4 acc_o[8] = {};
  float m_run[4] = {-1e30f, -1e30f, -1e30f, -1e30f};
  float l_run[4] = {0.f, 0.f, 0.f, 0.f};

  const unsigned short* kbase = xk + ((size_t)(b * 2048) * 8 + hkv) * 128;
  const unsigned short* vbase = xv + ((size_t)(b * 2048) * 8 + hkv) * 128;
  unsigned short* pw = Plds + wave * 16 * 72;

  for (int kt = 0; kt <= bx; ++kt) {
    const int ks = kt * 64;
    const bool diag = (kt == bx);
    __syncthreads();  // previous tile's LDS reads done
    // stage K tile [64][128] -> Klds padded
#pragma unroll
    for (int i = 0; i < 4; ++i) {
      int cid = i * 256 + tid;
      int r = cid >> 4, cc = cid & 15;
      short8_t kv = *(const short8_t*)(kbase + (size_t)(ks + r) * 1024 + cc * 8);
      *(short8_t*)(Klds + r * 136 + cc * 8) = kv;
    }
    // stage V tile transposed -> VT[hd][k] padded (pairs of rows -> b32 writes)
#pragma unroll
    for (int i = 0; i < 2; ++i) {
      int t2 = i * 256 + tid;
      int rp = t2 >> 4, cc = t2 & 15;
      int r = rp * 2;
      const unsigned short* vg = vbase + (size_t)(ks + r) * 1024 + cc * 8;
      short8_t v0 = *(const short8_t*)(vg);
      short8_t v1 = *(const short8_t*)(vg + 1024);
#pragma unroll
      for (int j = 0; j < 8; ++j) {
        unsigned int w = (unsigned int)(unsigned short)v0[j] |
                         ((unsigned int)(unsigned short)v1[j] << 16);
        *(unsigned int*)(VT + (cc * 8 + j) * 72 + r) = w;
      }
    }
    __syncthreads();

    // QK^T: scores S[16 q][64 k] per wave
    f32x4 sc[4] = {};
#pragma unroll
    for (int s = 0; s < 4; ++s) {
#pragma unroll
      for (int kb = 0; kb < 4; ++kb) {
        short8_t kf = *(const short8_t*)(Klds + (kb * 16 + ln) * 136 + s * 32 + g * 8);
        sc[kb] = mfma16(qf[s], kf, sc[kb]);
      }
    }
    // scale + causal mask
    const int rowg = q0 + wave * 16 + g * 4;
#pragma unroll
    for (int kb = 0; kb < 4; ++kb) {
      int colg = ks + kb * 16 + ln;
#pragma unroll
      for (int r = 0; r < 4; ++r) {
        float v = sc[kb][r] * SCALE;
        if (diag && colg > rowg + r) v = -1e30f;
        sc[kb][r] = v;
      }
    }
    // online softmax (16-lane groups hold 16 cols for rows g*4+r)
    float corr[4];
#pragma unroll
    for (int r = 0; r < 4; ++r) {
      float m = fmaxf(fmaxf(sc[0][r], sc[1][r]), fmaxf(sc[2][r], sc[3][r]));
#pragma unroll
      for (int off = 8; off >= 1; off >>= 1) m = fmaxf(m, __shfl_xor(m, off));
      float mn = fmaxf(m_run[r], m);
      float c = __expf(m_run[r] - mn);
      m_run[r] = mn;
      float ssum = 0.f;
#pragma unroll
      for (int kb = 0; kb < 4; ++kb) {
        float pv = __expf(sc[kb][r] - mn);
        sc[kb][r] = pv;
        ssum += pv;
      }
#pragma unroll
      for (int off = 8; off >= 1; off >>= 1) ssum += __shfl_xor(ssum, off);
      l_run[r] = l_run[r] * c + ssum;
      corr[r] = c;
    }
#pragma unroll
    for (int cb = 0; cb < 8; ++cb) {
      f32x4 t = acc_o[cb];
      t[0] *= corr[0]; t[1] *= corr[1]; t[2] *= corr[2]; t[3] *= corr[3];
      acc_o[cb] = t;
    }
    // P -> bf16 -> per-wave LDS [16 q][64 k] (stride 72)
#pragma unroll
    for (int kb = 0; kb < 4; ++kb)
#pragma unroll
      for (int r = 0; r < 4; ++r)
        pw[(g * 4 + r) * 72 + kb * 16 + ln] = f2b(sc[kb][r]);
    // PV: O += P * V
#pragma unroll
    for (int st = 0; st < 2; ++st) {
      short8_t pa = *(const short8_t*)(pw + ln * 72 + st * 32 + g * 8);
#pragma unroll
      for (int cb = 0; cb < 8; ++cb) {
        short8_t vf = *(const short8_t*)(VT + (cb * 16 + ln) * 72 + st * 32 + g * 8);
        acc_o[cb] = mfma16(pa, vf, acc_o[cb]);
      }
    }
  }

  float linv[4];
#pragma unroll
  for (int r = 0; r < 4; ++r) linv[r] = 1.0f / l_run[r];
  unsigned short* ob = ao + ((size_t)(b * 2048 + q0 + wave * 16 + g * 4) * 32 + h) * 128;
#pragma unroll
  for (int cb = 0; cb < 8; ++cb)
#pragma unroll
    for (int r = 0; r < 4; ++r)
      ob[(size_t)r * 4096 + cb * 16 + ln] = f2b(acc_o[cb][r] * linv[r]);
}

// ---------------- launch ----------------
extern "C" void kernel_launch(void* const* d_in, const int* in_sizes, int n_in,
                              void* d_out, int out_size, void* d_ws, size_t ws_size,
                              hipStream_t stream) {
  const float* x  = (const float*)d_in[0];
  const float* wq = (const float*)d_in[1];
  const float* wk = (const float*)d_in[2];
  const float* wv = (const float*)d_in[3];
  const float* wo = (const float*)d_in[4];
  const float* fr = (const float*)d_in[7];
  float* out = (float*)d_out;

  char* ws = (char*)d_ws;
  unsigned short* xb  = (unsigned short*)(ws);               // 33.5MB; reused as ao
  unsigned short* wqb = (unsigned short*)(ws + 33554432);    // 33.5MB; reused as wob
  unsigned short* wkb = (unsigned short*)(ws + 67108864);    // 8.4MB
  unsigned short* wvb = (unsigned short*)(ws + 75497472);    // 8.4MB
  unsigned short* xq  = (unsigned short*)(ws + 83886080);    // 33.5MB
  unsigned short* xk  = (unsigned short*)(ws + 117440512);   // 8.4MB
  unsigned short* xv  = (unsigned short*)(ws + 125829120);   // 8.4MB (total 128MiB)
  unsigned short* ao  = xb;
  unsigned short* wob = wqb;

  dim3 blk(256);
  cvt_kernel<<<dim3(1024), blk, 0, stream>>>(x,  xb,  16777216 / 4);
  cvt_kernel<<<dim3(1024), blk, 0, stream>>>(wq, wqb, 16777216 / 4);
  cvt_kernel<<<dim3(512),  blk, 0, stream>>>(wk, wkb, 4194304 / 4);
  cvt_kernel<<<dim3(512),  blk, 0, stream>>>(wv, wvb, 4194304 / 4);

  gemm_qkv_kernel<<<dim3(48, 32), blk, 0, stream>>>(xb, wqb, wkb, wvb, xq, xk, xv);

  rope_kernel<32><<<dim3(2048), blk, 0, stream>>>(xq, fr, 2097152);
  rope_kernel<8><<<dim3(512),  blk, 0, stream>>>(xk, fr, 524288);

  cvt_kernel<<<dim3(1024), blk, 0, stream>>>(wo, wob, 16777216 / 4);  // after QKV GEMM (reuses wqb)

  attn_kernel<<<dim3(32, 32, 2), blk, 0, stream>>>(xq, xk, xv, ao);   // ao reuses xb

  gemm_o_kernel<<<dim3(32, 32), blk, 0, stream>>>(ao, wob, out);
}